// Round 10
// baseline (533.585 us; speedup 1.0000x reference)
//
#include <hip/hip_runtime.h>
#include <stdint.h>

// ============================================================================
// LoRA Multihead Attention, MI355X / gfx950.  Round 19.
// R18 post-mortem: 472us total; attn_pv 126us (best), Occ 22% = 2 waves/SIMD,
// Mfma 10.6%.  MFMA-ideal ~17us + VALU ~10us -> latency-bound: 2 waves/SIMD
// can't hide L2-load -> MFMA -> exp -> LDS -> barrier chains.  R16 lesson:
// keep the 128x128 tile (K-reuse); don't clamp VGPR.
// R19: 8-wave (512-thread) blocks, SAME tile: per-wave j-slice 32 for QK^T,
// 16 q-rows for PV; per-thread sacc halves to 32 regs (~104 total, fits the
// 512-thread default 128-VGPR budget per R8 evidence).  Grid 512 -> 2
// blocks/CU x 8 waves = 4 waves/SIMD (2x R18's hiding, same traffic).
// wmean2 likewise (32q x 64j per wave, still zero LDS/barriers).
// Also: 3 weight packs merged into one dispatch.
// Predict: attn_pv Occ ~44%, dur 126 -> ~85us; wmean2 ~95 -> ~65; total
// 472 -> ~400-425us.
// ============================================================================

typedef __attribute__((ext_vector_type(8))) short short8;   // 8 x bf16 (4 VGPR)
typedef __attribute__((ext_vector_type(4))) float f32x4;    // MFMA C/D

#define LORA_SCALING 4.0f   // ALPHA/R = 32/8
#define FTINY 1.1754943508222875e-38f

static __device__ __forceinline__ unsigned short f2bf(float f){ // RN-even
  unsigned u = __float_as_uint(f);
  u += 0x7fffu + ((u >> 16) & 1u);
  return (unsigned short)(u >> 16);
}
static __device__ __forceinline__ float bflo(unsigned u){ return __uint_as_float(u << 16); }
static __device__ __forceinline__ float bfhi(unsigned u){ return __uint_as_float(u & 0xffff0000u); }
static __device__ __forceinline__ unsigned pk2(float lo, float hi){
  return (unsigned)f2bf(lo) | ((unsigned)f2bf(hi) << 16);
}
static __device__ __forceinline__ unsigned cvtpk(float lo, float hi){ // RNE pack
  unsigned r;
  asm("v_cvt_pk_bf16_f32 %0, %1, %2" : "=v"(r) : "v"(lo), "v"(hi));
  return r;
}
static __device__ __forceinline__ void gload16(const void* g, void* l){
  __builtin_amdgcn_global_load_lds(
      (const __attribute__((address_space(1))) unsigned int*)g,
      (__attribute__((address_space(3))) unsigned int*)l, 16, 0, 0);
}

union S8U { short8 v; uint2 u[2]; };

// ---------------------------------------------------------------------------
// pack_bf16: fp32 -> bf16 (RN-even), 8 elems/thread.  pack3: z picks src.
// ---------------------------------------------------------------------------
__global__ __launch_bounds__(256) void pack_bf16(const float* __restrict__ src,
                                                 unsigned short* __restrict__ dst)
{
  const size_t i = (size_t)blockIdx.x * 256 + threadIdx.x;   // 8-elem group
  const float4 f0 = ((const float4*)src)[i*2];
  const float4 f1 = ((const float4*)src)[i*2 + 1];
  ((uint4*)dst)[i] = make_uint4(pk2(f0.x,f0.y), pk2(f0.z,f0.w),
                                pk2(f1.x,f1.y), pk2(f1.z,f1.w));
}
__global__ __launch_bounds__(256) void pack3_bf16(
    const float* __restrict__ s0, const float* __restrict__ s1, const float* __restrict__ s2,
    unsigned short* __restrict__ d0, unsigned short* __restrict__ d1,
    unsigned short* __restrict__ d2)
{
  const int z = blockIdx.y;
  const float* src = (z==0)?s0:((z==1)?s1:s2);
  unsigned short* dst = (z==0)?d0:((z==1)?d1:d2);
  const size_t i = (size_t)blockIdx.x * 256 + threadIdx.x;
  const float4 f0 = ((const float4*)src)[i*2];
  const float4 f1 = ((const float4*)src)[i*2 + 1];
  ((uint4*)dst)[i] = make_uint4(pk2(f0.x,f0.y), pk2(f0.z,f0.w),
                                pk2(f1.x,f1.y), pk2(f1.z,f1.w));
}

// ---------------------------------------------------------------------------
// xa[t][r] = sum_i x[t][i] * A[r][i]   (fp32 out), K=1024, R=8.  X is bf16.
// ---------------------------------------------------------------------------
__global__ __launch_bounds__(256) void xa_kernel(const unsigned short* __restrict__ X,
                                                 const float* __restrict__ A,
                                                 float* __restrict__ xa)
{
  __shared__ float red[4][8];
  const int t = blockIdx.x, tid = threadIdx.x;
  const int lane = tid & 63, wid = tid >> 6;

  const uint2 xr = *(const uint2*)(X + (size_t)t*1024 + tid*4);
  const float x0 = bflo(xr.x), x1 = bfhi(xr.x), x2 = bflo(xr.y), x3 = bfhi(xr.y);

  float acc[8];
#pragma unroll
  for (int r = 0; r < 8; ++r) {
    const float4 ar = *(const float4*)(A + (size_t)r*1024 + tid*4);
    acc[r] = x0*ar.x + x1*ar.y + x2*ar.z + x3*ar.w;
  }
#pragma unroll
  for (int r = 0; r < 8; ++r) {
    float v = acc[r];
#pragma unroll
    for (int off = 32; off > 0; off >>= 1) v += __shfl_xor(v, off, 64);
    if (lane == 0) red[wid][r] = v;
  }
  __syncthreads();
  if (tid < 8) xa[(size_t)t*8 + tid] = red[0][tid] + red[1][tid] + red[2][tid] + red[3][tid];
}

// ---------------------------------------------------------------------------
// C = X(4096x1024 bf16) * W(1024x1024 bf16)^T + bias + 4 * xa * Blora^T.
// MFMA 16x16x32, 128x128 tile, BK=32.  Staging via global_load_lds(16).
// z==0 output scaled by scale0 (0.125 for Q, exact bf16 exponent shift).
// ---------------------------------------------------------------------------
__global__ __launch_bounds__(256) void gemm_bf16(
    const unsigned short* __restrict__ Abf,
    const unsigned short* __restrict__ W0bf, const unsigned short* __restrict__ W1bf,
    const unsigned short* __restrict__ W2bf,
    const float* __restrict__ B0, const float* __restrict__ B1, const float* __restrict__ B2,
    const float* __restrict__ xa0, const float* __restrict__ xa1, const float* __restrict__ xa2,
    const float* __restrict__ L0, const float* __restrict__ L1, const float* __restrict__ L2,
    void* __restrict__ C0, void* __restrict__ C1, void* __restrict__ C2,
    int fp32out, float scale0)
{
  const int z = blockIdx.z;
  const unsigned short* W = (z==0)?W0bf:((z==1)?W1bf:W2bf);
  const float* Bb = (z==0)?B0:((z==1)?B1:B2);
  const float* xa = (z==0)?xa0:((z==1)?xa1:xa2);
  const float* Lb = (z==0)?L0:((z==1)?L1:L2);
  void*        C  = (z==0)?C0:((z==1)?C1:C2);
  const bool vtw = (z == 2);
  const float sc = (z == 0) ? scale0 : 1.0f;

  __shared__ alignas(16) unsigned short As[128*32];
  __shared__ alignas(16) unsigned short Bs[128*32];

  const int tid = threadIdx.x;
  const int lane = tid & 63, wid = tid >> 6;
  const int quad = lane >> 4, lm = lane & 15;
  const int t0 = blockIdx.x * 128, n0 = blockIdx.y * 128;
  const int wm = (wid & 1) * 64, wn = (wid >> 1) * 64;

  // 16B chunk ids for staging (row = c>>2, col elems = (c&3)*8)
  const int c0 = tid, c1 = tid + 256;
  const int r0c = c0 >> 2, e0c = (c0 & 3) * 8;
  const int r1c = c1 >> 2, e1c = (c1 & 3) * 8;

  f32x4 acc[4][4];
#pragma unroll
  for (int i = 0; i < 4; ++i)
#pragma unroll
    for (int j = 0; j < 4; ++j) acc[i][j] = 0.f;

  for (int kt = 0; kt < 32; ++kt) {
    const int k0 = kt * 32;
    __syncthreads();   // previous iteration's fragment reads complete
    gload16(Abf + (size_t)(t0 + r0c)*1024 + k0 + e0c, &As[c0*8]);
    gload16(Abf + (size_t)(t0 + r1c)*1024 + k0 + e1c, &As[c1*8]);
    gload16(W   + (size_t)(n0 + r0c)*1024 + k0 + e0c, &Bs[c0*8]);
    gload16(W   + (size_t)(n0 + r1c)*1024 + k0 + e1c, &Bs[c1*8]);
    __syncthreads();   // vmcnt(0) drained before barrier -> LDS visible
    short8 a[4], b[4];
#pragma unroll
    for (int i = 0; i < 4; ++i) a[i] = *(const short8*)&As[(wm + i*16 + lm)*32 + quad*8];
#pragma unroll
    for (int j = 0; j < 4; ++j) b[j] = *(const short8*)&Bs[(wn + j*16 + lm)*32 + quad*8];
#pragma unroll
    for (int i = 0; i < 4; ++i)
#pragma unroll
      for (int j = 0; j < 4; ++j)
        acc[i][j] = __builtin_amdgcn_mfma_f32_16x16x32_bf16(a[i], b[j], acc[i][j], 0, 0, 0);
  }

  // epilogue: (bias + 4.0 * (xa . Blora) + acc) * sc
#pragma unroll
  for (int j = 0; j < 4; ++j) {
    const int col = n0 + wn + j*16 + lm;
    const float bias = Bb[col];
    const float4 u0 = ((const float4*)(Lb + (size_t)col*8))[0];
    const float4 u1 = ((const float4*)(Lb + (size_t)col*8))[1];
#pragma unroll
    for (int i = 0; i < 4; ++i) {
#pragma unroll
      for (int r = 0; r < 4; ++r) {
        const int row = t0 + wm + i*16 + quad*4 + r;
        const float* xr = xa + (size_t)row*8;
        const float lora = xr[0]*u0.x + xr[1]*u0.y + xr[2]*u0.z + xr[3]*u0.w
                         + xr[4]*u1.x + xr[5]*u1.y + xr[6]*u1.z + xr[7]*u1.w;
        const float val = (acc[i][j][r] + bias + LORA_SCALING*lora) * sc;
        if (fp32out) {
          ((float*)C)[(size_t)row*1024 + col] = val;
        } else if (vtw) {
          // t = l*2 + n  ->  Vt[(n*1024 + e)*2048 + l]
          ((unsigned short*)C)[((size_t)(row & 1) * 1024 + col) * 2048 + (row >> 1)] = f2bf(val);
        } else {
          ((unsigned short*)C)[(size_t)row*1024 + col] = f2bf(val);
        }
      }
    }
  }
}

// ---------------------------------------------------------------------------
// attn_pv: 512 threads = 8 waves; block = (128 q, n, h), grid (16,2,16).
// 2 blocks/CU x 8 waves = 4 waves/SIMD.  Q pre-scaled -> e = exp(S).
// Per 128-j tile: wave (wq=wid>>2, wj=wid&3) computes QK^T for its 32-j
// slice x 64-q half (sacc[2][4]) -> exp+mask+cvt_pk -> Es[128q][132j];
// PV: wave owns 16 q-rows (r0 = wid*16+lm).  2 barriers/tile.
// End: l reduce (quad shfl + 4 wj slices via LDS), ctx = oacc*rinv, msl.
// ---------------------------------------------------------------------------
__global__ __launch_bounds__(512) void attn_pv(
    const unsigned short* __restrict__ qb, const unsigned short* __restrict__ kb,
    const unsigned short* __restrict__ vt, const int* __restrict__ mask,
    unsigned short* __restrict__ ctx, float* __restrict__ msl)
{
  __shared__ alignas(16) unsigned short Es[128*132];   // e-tile [q][j], pad 4
  __shared__ unsigned char mlds[2048];
  __shared__ float lred[4][128];

  const int tid = threadIdx.x, lane = tid & 63, wid = tid >> 6;  // wid 0..7
  const int quad = lane >> 4, lm = lane & 15;
  const int q0 = blockIdx.x * 128, n = blockIdx.y, h = blockIdx.z;
  const int wq = wid >> 2, wj = wid & 3;

  // stage mask flags for all 2048 j (512 threads x 4)
  {
    const int4 m0 = *(const int4*)(mask + n*2048 + tid*4);
    mlds[tid*4+0] = (m0.x != 0); mlds[tid*4+1] = (m0.y != 0);
    mlds[tid*4+2] = (m0.z != 0); mlds[tid*4+3] = (m0.w != 0);
  }

  // Q as B-operand fragments for this wave's 64-q half
  short8 bq[4][2];
#pragma unroll
  for (int q_t = 0; q_t < 4; ++q_t) {
    const unsigned short* qg = qb + ((size_t)(q0 + wq*64 + q_t*16 + lm)*2 + n)*1024 + h*64 + quad*8;
    bq[q_t][0] = *(const short8*)qg;
    bq[q_t][1] = *(const short8*)(qg + 32);
  }

  float lsum[4] = {0.f, 0.f, 0.f, 0.f};
  f32x4 oacc[4];
#pragma unroll
  for (int dt = 0; dt < 4; ++dt) oacc[dt] = 0.f;

  for (int jt = 0; jt < 16; ++jt) {
    const int j0 = jt * 128;
    __syncthreads();   // Es free (prev PV reads done); mlds visible (jt==0)

    // ---- QK^T swapped: sacc[j_t][q_t], rows j (wave's 32), cols q ----
    f32x4 sacc[2][4];
#pragma unroll
    for (int a = 0; a < 2; ++a)
#pragma unroll
      for (int b = 0; b < 4; ++b) sacc[a][b] = 0.f;
#pragma unroll
    for (int kt = 0; kt < 2; ++kt) {
      short8 ak[2];
#pragma unroll
      for (int j_t = 0; j_t < 2; ++j_t)
        ak[j_t] = *(const short8*)(kb + ((size_t)(j0 + wj*32 + j_t*16 + lm)*2 + n)*1024 + h*64 + kt*32 + quad*8);
#pragma unroll
      for (int j_t = 0; j_t < 2; ++j_t)
#pragma unroll
        for (int q_t = 0; q_t < 4; ++q_t)
          sacc[j_t][q_t] = __builtin_amdgcn_mfma_f32_16x16x32_bf16(ak[j_t], bq[q_t][kt], sacc[j_t][q_t], 0, 0, 0);
    }
    // ---- exp + mask + lsum + Es writes (cvt_pk) ----
#pragma unroll
    for (int j_t = 0; j_t < 2; ++j_t) {
      const int jrow = wj*32 + j_t*16 + quad*4;            // local j of rows r=0..3
      const uchar4 mk = *(const uchar4*)&mlds[j0 + jrow];
#pragma unroll
      for (int q_t = 0; q_t < 4; ++q_t) {
        const float e0 = mk.x ? 0.f : __expf(sacc[j_t][q_t][0]);
        const float e1 = mk.y ? 0.f : __expf(sacc[j_t][q_t][1]);
        const float e2 = mk.z ? 0.f : __expf(sacc[j_t][q_t][2]);
        const float e3 = mk.w ? 0.f : __expf(sacc[j_t][q_t][3]);
        lsum[q_t] += (e0 + e1) + (e2 + e3);
        const int qcol = wq*64 + q_t*16 + lm;
        *(uint2*)&Es[qcol*132 + jrow] = make_uint2(cvtpk(e0, e1), cvtpk(e2, e3));
      }
    }
    __syncthreads();   // Es visible
    // ---- PV: wave reads its 16 q rows; B = V^T from global ----
#pragma unroll
    for (int kk = 0; kk < 4; ++kk) {
      S8U ae;
      const int r0 = wid*16 + lm;
      ae.u[0] = *(const uint2*)&Es[r0*132 + kk*32 + quad*8];
      ae.u[1] = *(const uint2*)&Es[r0*132 + kk*32 + quad*8 + 4];
      const unsigned short* vbase = vt + (size_t)((n*16 + h)*64)*2048 + j0 + kk*32 + quad*8;
#pragma unroll
      for (int dt = 0; dt < 4; ++dt) {
        const short8 bv = *(const short8*)(vbase + (size_t)(dt*16 + lm)*2048);
        oacc[dt] = __builtin_amdgcn_mfma_f32_16x16x32_bf16(ae.v, bv, oacc[dt], 0, 0, 0);
      }
    }
  }

  // ---- l reduction: quads via shuffle, 4 wj slices via LDS ----
#pragma unroll
  for (int q_t = 0; q_t < 4; ++q_t) {
    float v = lsum[q_t];
    v += __shfl_xor(v, 16, 64);
    v += __shfl_xor(v, 32, 64);
    if (quad == 0 && wq == 0) lred[wj][q_t*16 + lm] = v;
  }
  __syncthreads();
  // wq==1 waves add their halves
#pragma unroll
  for (int q_t = 0; q_t < 4; ++q_t) {
    float v = lsum[q_t];
    v += __shfl_xor(v, 16, 64);
    v += __shfl_xor(v, 32, 64);
    if (quad == 0 && wq == 1) lred[wj][64 + q_t*16 + lm] = v;
  }
  __syncthreads();
  if (tid < 128) {
    const float l = lred[0][tid] + lred[1][tid] + lred[2][tid] + lred[3][tid];
    const float rinv = 1.0f / fmaxf(l, FTINY);
    lred[0][tid] = rinv;
    msl[(size_t)(h*2 + n)*2048 + q0 + tid] = rinv;
  }
  __syncthreads();
  // ---- scale + write ctx (wave's 16 q rows) ----
  {
    const int rb = wid*16 + quad*4;
    const float4 rv4 = *(const float4*)&lred[0][rb];
    const float rva[4] = {rv4.x, rv4.y, rv4.z, rv4.w};
#pragma unroll
    for (int dt = 0; dt < 4; ++dt) {
#pragma unroll
      for (int r = 0; r < 4; ++r) {
        ctx[((size_t)(q0 + rb + r)*2 + n)*1024 + h*64 + dt*16 + lm] =
            f2bf(oacc[dt][r] * rva[r]);
      }
    }
  }
}

// ---------------------------------------------------------------------------
// wmean2: 512 threads = 8 waves; block = (128 q, 128 j, n), grid (16,16,2).
// Wave = (wq=wid>>1: 32q, wj=wid&1: 64j).  Loop h.  Zero LDS, zero barriers.
// Q pre-scaled -> e = exp(S).
// ---------------------------------------------------------------------------
__global__ __launch_bounds__(512) void wmean2(
    const unsigned short* __restrict__ qb, const unsigned short* __restrict__ kb,
    const int* __restrict__ mask, const float* __restrict__ msl,
    float* __restrict__ wout)
{
  const int tid = threadIdx.x, lane = tid & 63, wid = tid >> 6;
  const int quad = lane >> 4, lm = lane & 15;
  const int q0 = blockIdx.x * 128, j0 = blockIdx.y * 128, n = blockIdx.z;
  const int wq = wid >> 1, wj = wid & 1;   // wq 0..3 (32q), wj 0..1 (64j)

  unsigned fm = 0;
#pragma unroll
  for (int j_t = 0; j_t < 4; ++j_t)
    fm |= (mask[n*2048 + j0 + wj*64 + j_t*16 + lm] != 0 ? 1u : 0u) << j_t;

  f32x4 wacc[2][4];
#pragma unroll
  for (int i = 0; i < 2; ++i)
#pragma unroll
    for (int j = 0; j < 4; ++j) wacc[i][j] = 0.f;

  for (int h = 0; h < 16; ++h) {
    short8 aq[2][2];
#pragma unroll
    for (int i = 0; i < 2; ++i) {
      const unsigned short* qg = qb + ((size_t)(q0 + wq*32 + i*16 + lm)*2 + n)*1024 + h*64 + quad*8;
      aq[i][0] = *(const short8*)qg;
      aq[i][1] = *(const short8*)(qg + 32);
    }
    float4 rv[2];
#pragma unroll
    for (int i = 0; i < 2; ++i)
      rv[i] = *(const float4*)&msl[(size_t)(h*2 + n)*2048 + q0 + wq*32 + i*16 + quad*4];
#pragma unroll
    for (int jh2 = 0; jh2 < 2; ++jh2) {
      short8 bk[2][2];
#pragma unroll
      for (int jtl = 0; jtl < 2; ++jtl) {
        const unsigned short* kg = kb + ((size_t)(j0 + wj*64 + (jh2*2 + jtl)*16 + lm)*2 + n)*1024 + h*64 + quad*8;
        bk[jtl][0] = *(const short8*)kg;
        bk[jtl][1] = *(const short8*)(kg + 32);
      }
      f32x4 sacc[2][2];
#pragma unroll
      for (int i = 0; i < 2; ++i)
#pragma unroll
        for (int jtl = 0; jtl < 2; ++jtl) sacc[i][jtl] = 0.f;
#pragma unroll
      for (int kt = 0; kt < 2; ++kt)
#pragma unroll
        for (int i = 0; i < 2; ++i)
#pragma unroll
          for (int jtl = 0; jtl < 2; ++jtl)
            sacc[i][jtl] = __builtin_amdgcn_mfma_f32_16x16x32_bf16(aq[i][kt], bk[jtl][kt], sacc[i][jtl], 0, 0, 0);
#pragma unroll
      for (int i = 0; i < 2; ++i) {
        const float rva[4] = {rv[i].x, rv[i].y, rv[i].z, rv[i].w};
#pragma unroll
        for (int jtl = 0; jtl < 2; ++jtl) {
          const int j_t = jh2*2 + jtl;
          const bool mskd = (fm >> j_t) & 1u;
#pragma unroll
          for (int r = 0; r < 4; ++r) {
            const float e = mskd ? 0.f : __expf(sacc[i][jtl][r]) * rva[r];
            wacc[i][j_t][r] += e;
          }
        }
      }
    }
  }
  // ---- store head-mean ----
#pragma unroll
  for (int i = 0; i < 2; ++i)
#pragma unroll
    for (int j_t = 0; j_t < 4; ++j_t)
#pragma unroll
      for (int r = 0; r < 4; ++r) {
        const int row = q0 + wq*32 + i*16 + quad*4 + r;
        const int col = j0 + wj*64 + j_t*16 + lm;
        wout[((size_t)row*2 + n)*2048 + col] = wacc[i][j_t][r] * 0.0625f;
      }
}

// ---------------------------------------------------------------------------
// ctx_copy: move ctx (bf16, 8.4 MB) from d_out region into kbuf.
// ---------------------------------------------------------------------------
__global__ __launch_bounds__(256) void ctx_copy(const uint4* __restrict__ src,
                                                uint4* __restrict__ dst)
{
  const size_t i = (size_t)blockIdx.x * 256 + threadIdx.x;
  dst[i] = src[i];
}

// ---------------------------------------------------------------------------
extern "C" void kernel_launch(void* const* d_in, const int* in_sizes, int n_in,
                              void* d_out, int out_size, void* d_ws, size_t ws_size,
                              hipStream_t stream) {
  const float* x    = (const float*)d_in[0];
  const int*   mask = (const int*)d_in[1];
  const float* Wq = (const float*)d_in[2];  const float* bq = (const float*)d_in[3];
  const float* Aq = (const float*)d_in[4];  const float* Bq = (const float*)d_in[5];
  const float* Wk = (const float*)d_in[6];  const float* bk = (const float*)d_in[7];
  const float* Ak = (const float*)d_in[8];  const float* Bk = (const float*)d_in[9];
  const float* Wv = (const float*)d_in[10]; const float* bv = (const float*)d_in[11];
  const float* Av = (const float*)d_in[12]; const float* Bv = (const float*)d_in[13];
  const float* Wo = (const float*)d_in[14]; const float* bo = (const float*)d_in[15];
  const float* Ao = (const float*)d_in[16]; const float* Bo = (const float*)d_in[17];

  float* outF = (float*)d_out;          // fp32: [4194304 attn | 8388608 weights]
  float* woutF = outF + 4194304;

  // d_ws: 24 MiB of bf16 internals
  unsigned short* kbuf = (unsigned short*)d_ws;   // [0, 8 MiB)
  unsigned short* vtb  = kbuf + 4194304;          // [8, 16 MiB)
  unsigned short* qbuf = vtb  + 4194304;          // [16, 24 MiB)

  // xaq/xak/xav at head of fp32 weights region (dead before wout overwrites)
  float* xaq = woutF;
  float* xak = xaq + 32768;
  float* xav = xak + 32768;

  // bf16 operand packs parked in the attn-output region (floats [0, 4194304)):
  //   Xbf  floats [0, 2097152)        -- dead after QKV gemm
  //   Wqbf floats [2097152, 2621440)  -- dead after QKV gemm
  //   Wkbf floats [2621440, 3145728)
  //   Wvbf floats [3145728, 3670016)
  // attn_pv then writes ctx16 at [0, 2097152) and msl at [2359296, 2424832).
  unsigned short* Xbf  = (unsigned short*)outF;
  unsigned short* Wqbf = (unsigned short*)(outF + 2097152);
  unsigned short* Wkbf = (unsigned short*)(outF + 2621440);
  unsigned short* Wvbf = (unsigned short*)(outF + 3145728);
  unsigned short* ctx16 = (unsigned short*)outF;
  float* msl = outF + 2359296;

  // xao overlays vtb[0,128KB); Wo-bf16 at vtb bytes [1MB,3MB) (V dead then)
  float* xao = (float*)vtb;
  unsigned short* Wobf = vtb + 524288;

  pack_bf16<<<dim3(2048), dim3(256), 0, stream>>>(x, Xbf);
  pack3_bf16<<<dim3(512, 3), dim3(256), 0, stream>>>(Wq, Wk, Wv, Wqbf, Wkbf, Wvbf);

  xa_kernel<<<dim3(4096), dim3(256), 0, stream>>>(Xbf, Aq, xaq);
  xa_kernel<<<dim3(4096), dim3(256), 0, stream>>>(Xbf, Ak, xak);
  xa_kernel<<<dim3(4096), dim3(256), 0, stream>>>(Xbf, Av, xav);

  // Q output pre-scaled by 0.125 (exact bf16 exponent shift)
  gemm_bf16<<<dim3(32, 8, 3), dim3(256), 0, stream>>>(
      Xbf, Wqbf, Wkbf, Wvbf, bq, bk, bv, xaq, xak, xav, Bq, Bk, Bv,
      qbuf, kbuf, vtb, 0, 0.125f);

  attn_pv<<<dim3(16, 2, 16), dim3(512), 0, stream>>>(qbuf, kbuf, vtb, mask, ctx16, msl);

  pack_bf16<<<dim3(512), dim3(256), 0, stream>>>(Wo, Wobf);   // vtb dead now

  wmean2<<<dim3(16, 16, 2), dim3(512), 0, stream>>>(qbuf, kbuf, mask, msl, woutF);

  // kbuf dead after wmean2 -> move ctx there
  ctx_copy<<<dim3(2048), dim3(256), 0, stream>>>((const uint4*)ctx16, (uint4*)kbuf);

  xa_kernel<<<dim3(4096), dim3(256), 0, stream>>>(kbuf, Ao, xao);

  gemm_bf16<<<dim3(32, 8, 1), dim3(256), 0, stream>>>(
      kbuf, Wobf, Wobf, Wobf, bo, bo, bo, xao, xao, xao, Bo, Bo, Bo,
      outF, outF, outF, 1, 1.0f);
}

// Round 11
// 474.181 us; speedup vs baseline: 1.1253x; 1.1253x over previous
//
#include <hip/hip_runtime.h>
#include <stdint.h>

// ============================================================================
// LoRA Multihead Attention, MI355X / gfx950.  Round 20.
// R19 post-mortem: 512-thread blocks ALSO pinned to VGPR=64 (any >256-thread
// block on this toolchain) -> reload chains, 161us.  Empirical law for
// attn_pv: fat regs + fat tile at 2 blocks/CU beats every higher-occupancy
// variant (126 @ VGPR116 vs 157/161/213).  Per-wave critical path is the
// limit, not wave count.
// R20: R18's exact shape + double-buffered Es, ONE barrier per j-tile,
// cross-tile ILP: issue K-loads(t+1) -> PV(t) (hides K latency under V
// loads + 32 MFMA) -> QK^T(t+1)+exp+write other buffer.  QK split into two
// j_t-pair passes (live sacc 32 regs, peak ~140 VGPR).  Barriers 33->20.
// LDS 70.7KB -> still 2 blocks/CU.  wmean2/gemm/xa = R18 exact (keep R19's
// pack3 merge).
// Predict: attn_pv 126 -> ~95-105us (Mfma ~14%), total 472 -> ~440-455us.
// ============================================================================

typedef __attribute__((ext_vector_type(8))) short short8;   // 8 x bf16 (4 VGPR)
typedef __attribute__((ext_vector_type(4))) float f32x4;    // MFMA C/D

#define LORA_SCALING 4.0f   // ALPHA/R = 32/8
#define FTINY 1.1754943508222875e-38f

static __device__ __forceinline__ unsigned short f2bf(float f){ // RN-even
  unsigned u = __float_as_uint(f);
  u += 0x7fffu + ((u >> 16) & 1u);
  return (unsigned short)(u >> 16);
}
static __device__ __forceinline__ float bflo(unsigned u){ return __uint_as_float(u << 16); }
static __device__ __forceinline__ float bfhi(unsigned u){ return __uint_as_float(u & 0xffff0000u); }
static __device__ __forceinline__ unsigned pk2(float lo, float hi){
  return (unsigned)f2bf(lo) | ((unsigned)f2bf(hi) << 16);
}
static __device__ __forceinline__ unsigned cvtpk(float lo, float hi){ // RNE pack
  unsigned r;
  asm("v_cvt_pk_bf16_f32 %0, %1, %2" : "=v"(r) : "v"(lo), "v"(hi));
  return r;
}
static __device__ __forceinline__ void gload16(const void* g, void* l){
  __builtin_amdgcn_global_load_lds(
      (const __attribute__((address_space(1))) unsigned int*)g,
      (__attribute__((address_space(3))) unsigned int*)l, 16, 0, 0);
}

union S8U { short8 v; uint2 u[2]; };

// ---------------------------------------------------------------------------
// pack_bf16: fp32 -> bf16 (RN-even), 8 elems/thread.  pack3: z picks src.
// ---------------------------------------------------------------------------
__global__ __launch_bounds__(256) void pack_bf16(const float* __restrict__ src,
                                                 unsigned short* __restrict__ dst)
{
  const size_t i = (size_t)blockIdx.x * 256 + threadIdx.x;   // 8-elem group
  const float4 f0 = ((const float4*)src)[i*2];
  const float4 f1 = ((const float4*)src)[i*2 + 1];
  ((uint4*)dst)[i] = make_uint4(pk2(f0.x,f0.y), pk2(f0.z,f0.w),
                                pk2(f1.x,f1.y), pk2(f1.z,f1.w));
}
__global__ __launch_bounds__(256) void pack3_bf16(
    const float* __restrict__ s0, const float* __restrict__ s1, const float* __restrict__ s2,
    unsigned short* __restrict__ d0, unsigned short* __restrict__ d1,
    unsigned short* __restrict__ d2)
{
  const int z = blockIdx.y;
  const float* src = (z==0)?s0:((z==1)?s1:s2);
  unsigned short* dst = (z==0)?d0:((z==1)?d1:d2);
  const size_t i = (size_t)blockIdx.x * 256 + threadIdx.x;
  const float4 f0 = ((const float4*)src)[i*2];
  const float4 f1 = ((const float4*)src)[i*2 + 1];
  ((uint4*)dst)[i] = make_uint4(pk2(f0.x,f0.y), pk2(f0.z,f0.w),
                                pk2(f1.x,f1.y), pk2(f1.z,f1.w));
}

// ---------------------------------------------------------------------------
// xa[t][r] = sum_i x[t][i] * A[r][i]   (fp32 out), K=1024, R=8.  X is bf16.
// ---------------------------------------------------------------------------
__global__ __launch_bounds__(256) void xa_kernel(const unsigned short* __restrict__ X,
                                                 const float* __restrict__ A,
                                                 float* __restrict__ xa)
{
  __shared__ float red[4][8];
  const int t = blockIdx.x, tid = threadIdx.x;
  const int lane = tid & 63, wid = tid >> 6;

  const uint2 xr = *(const uint2*)(X + (size_t)t*1024 + tid*4);
  const float x0 = bflo(xr.x), x1 = bfhi(xr.x), x2 = bflo(xr.y), x3 = bfhi(xr.y);

  float acc[8];
#pragma unroll
  for (int r = 0; r < 8; ++r) {
    const float4 ar = *(const float4*)(A + (size_t)r*1024 + tid*4);
    acc[r] = x0*ar.x + x1*ar.y + x2*ar.z + x3*ar.w;
  }
#pragma unroll
  for (int r = 0; r < 8; ++r) {
    float v = acc[r];
#pragma unroll
    for (int off = 32; off > 0; off >>= 1) v += __shfl_xor(v, off, 64);
    if (lane == 0) red[wid][r] = v;
  }
  __syncthreads();
  if (tid < 8) xa[(size_t)t*8 + tid] = red[0][tid] + red[1][tid] + red[2][tid] + red[3][tid];
}

// ---------------------------------------------------------------------------
// C = X(4096x1024 bf16) * W(1024x1024 bf16)^T + bias + 4 * xa * Blora^T.
// MFMA 16x16x32, 128x128 tile, BK=32.  Staging via global_load_lds(16).
// z==0 output scaled by scale0 (0.125 for Q, exact bf16 exponent shift).
// ---------------------------------------------------------------------------
__global__ __launch_bounds__(256) void gemm_bf16(
    const unsigned short* __restrict__ Abf,
    const unsigned short* __restrict__ W0bf, const unsigned short* __restrict__ W1bf,
    const unsigned short* __restrict__ W2bf,
    const float* __restrict__ B0, const float* __restrict__ B1, const float* __restrict__ B2,
    const float* __restrict__ xa0, const float* __restrict__ xa1, const float* __restrict__ xa2,
    const float* __restrict__ L0, const float* __restrict__ L1, const float* __restrict__ L2,
    void* __restrict__ C0, void* __restrict__ C1, void* __restrict__ C2,
    int fp32out, float scale0)
{
  const int z = blockIdx.z;
  const unsigned short* W = (z==0)?W0bf:((z==1)?W1bf:W2bf);
  const float* Bb = (z==0)?B0:((z==1)?B1:B2);
  const float* xa = (z==0)?xa0:((z==1)?xa1:xa2);
  const float* Lb = (z==0)?L0:((z==1)?L1:L2);
  void*        C  = (z==0)?C0:((z==1)?C1:C2);
  const bool vtw = (z == 2);
  const float sc = (z == 0) ? scale0 : 1.0f;

  __shared__ alignas(16) unsigned short As[128*32];
  __shared__ alignas(16) unsigned short Bs[128*32];

  const int tid = threadIdx.x;
  const int lane = tid & 63, wid = tid >> 6;
  const int quad = lane >> 4, lm = lane & 15;
  const int t0 = blockIdx.x * 128, n0 = blockIdx.y * 128;
  const int wm = (wid & 1) * 64, wn = (wid >> 1) * 64;

  // 16B chunk ids for staging (row = c>>2, col elems = (c&3)*8)
  const int c0 = tid, c1 = tid + 256;
  const int r0c = c0 >> 2, e0c = (c0 & 3) * 8;
  const int r1c = c1 >> 2, e1c = (c1 & 3) * 8;

  f32x4 acc[4][4];
#pragma unroll
  for (int i = 0; i < 4; ++i)
#pragma unroll
    for (int j = 0; j < 4; ++j) acc[i][j] = 0.f;

  for (int kt = 0; kt < 32; ++kt) {
    const int k0 = kt * 32;
    __syncthreads();   // previous iteration's fragment reads complete
    gload16(Abf + (size_t)(t0 + r0c)*1024 + k0 + e0c, &As[c0*8]);
    gload16(Abf + (size_t)(t0 + r1c)*1024 + k0 + e1c, &As[c1*8]);
    gload16(W   + (size_t)(n0 + r0c)*1024 + k0 + e0c, &Bs[c0*8]);
    gload16(W   + (size_t)(n0 + r1c)*1024 + k0 + e1c, &Bs[c1*8]);
    __syncthreads();   // vmcnt(0) drained before barrier -> LDS visible
    short8 a[4], b[4];
#pragma unroll
    for (int i = 0; i < 4; ++i) a[i] = *(const short8*)&As[(wm + i*16 + lm)*32 + quad*8];
#pragma unroll
    for (int j = 0; j < 4; ++j) b[j] = *(const short8*)&Bs[(wn + j*16 + lm)*32 + quad*8];
#pragma unroll
    for (int i = 0; i < 4; ++i)
#pragma unroll
      for (int j = 0; j < 4; ++j)
        acc[i][j] = __builtin_amdgcn_mfma_f32_16x16x32_bf16(a[i], b[j], acc[i][j], 0, 0, 0);
  }

  // epilogue: (bias + 4.0 * (xa . Blora) + acc) * sc
#pragma unroll
  for (int j = 0; j < 4; ++j) {
    const int col = n0 + wn + j*16 + lm;
    const float bias = Bb[col];
    const float4 u0 = ((const float4*)(Lb + (size_t)col*8))[0];
    const float4 u1 = ((const float4*)(Lb + (size_t)col*8))[1];
#pragma unroll
    for (int i = 0; i < 4; ++i) {
#pragma unroll
      for (int r = 0; r < 4; ++r) {
        const int row = t0 + wm + i*16 + quad*4 + r;
        const float* xr = xa + (size_t)row*8;
        const float lora = xr[0]*u0.x + xr[1]*u0.y + xr[2]*u0.z + xr[3]*u0.w
                         + xr[4]*u1.x + xr[5]*u1.y + xr[6]*u1.z + xr[7]*u1.w;
        const float val = (acc[i][j][r] + bias + LORA_SCALING*lora) * sc;
        if (fp32out) {
          ((float*)C)[(size_t)row*1024 + col] = val;
        } else if (vtw) {
          // t = l*2 + n  ->  Vt[(n*1024 + e)*2048 + l]
          ((unsigned short*)C)[((size_t)(row & 1) * 1024 + col) * 2048 + (row >> 1)] = f2bf(val);
        } else {
          ((unsigned short*)C)[(size_t)row*1024 + col] = f2bf(val);
        }
      }
    }
  }
}

// ---------------------------------------------------------------------------
// attn_pv: block = (128 q, n, h), 256 thr, grid (16,2,16).  R18 shape with
// double-buffered Es + ONE barrier per j-tile + cross-tile ILP:
//   iter t: barrier; load K(t+1); PV(t) from Es[t&1] (hides K latency);
//           QK^T(t+1) in two j_t-pair passes -> exp -> Es[(t+1)&1].
// Q pre-scaled by 0.125 -> e = exp(S).  End: l reduce, ctx, msl.
// ---------------------------------------------------------------------------
__global__ __launch_bounds__(256) void attn_pv(
    const unsigned short* __restrict__ qb, const unsigned short* __restrict__ kb,
    const unsigned short* __restrict__ vt, const int* __restrict__ mask,
    unsigned short* __restrict__ ctx, float* __restrict__ msl)
{
  __shared__ alignas(16) unsigned short Es[2][128*132]; // e-tiles [q][j], pad 4
  __shared__ unsigned char mlds[2048];
  __shared__ float lred[2][128];

  const int tid = threadIdx.x, lane = tid & 63, wid = tid >> 6;  // wid 0..3
  const int quad = lane >> 4, lm = lane & 15;
  const int q0 = blockIdx.x * 128, n = blockIdx.y, h = blockIdx.z;
  const int wq = wid >> 1, wj = wid & 1;

  // stage mask flags for all 2048 j
  {
    const int4 m0 = *(const int4*)(mask + n*2048 + tid*8);
    const int4 m1 = *(const int4*)(mask + n*2048 + tid*8 + 4);
    mlds[tid*8+0] = (m0.x != 0); mlds[tid*8+1] = (m0.y != 0);
    mlds[tid*8+2] = (m0.z != 0); mlds[tid*8+3] = (m0.w != 0);
    mlds[tid*8+4] = (m1.x != 0); mlds[tid*8+5] = (m1.y != 0);
    mlds[tid*8+6] = (m1.z != 0); mlds[tid*8+7] = (m1.w != 0);
  }

  // Q as B-operand fragments, in registers for the whole block
  short8 bq[4][2];
#pragma unroll
  for (int q_t = 0; q_t < 4; ++q_t) {
    const unsigned short* qg = qb + ((size_t)(q0 + wq*64 + q_t*16 + lm)*2 + n)*1024 + h*64 + quad*8;
    bq[q_t][0] = *(const short8*)qg;
    bq[q_t][1] = *(const short8*)(qg + 32);
  }

  float lsum[4] = {0.f, 0.f, 0.f, 0.f};
  f32x4 oacc[2][4];
#pragma unroll
  for (int i2 = 0; i2 < 2; ++i2)
#pragma unroll
    for (int dt = 0; dt < 4; ++dt) oacc[i2][dt] = 0.f;

  __syncthreads();   // mlds visible

  // ---- prologue: QK^T(0) + exp -> Es[0] ----
#pragma unroll
  for (int jp = 0; jp < 2; ++jp) {          // j_t pairs {0,1},{2,3}
    f32x4 sacc[2][4];
#pragma unroll
    for (int a = 0; a < 2; ++a)
#pragma unroll
      for (int b = 0; b < 4; ++b) sacc[a][b] = 0.f;
#pragma unroll
    for (int kt = 0; kt < 2; ++kt) {
      short8 ak[2];
#pragma unroll
      for (int jl = 0; jl < 2; ++jl)
        ak[jl] = *(const short8*)(kb + ((size_t)(wj*64 + (jp*2+jl)*16 + lm)*2 + n)*1024 + h*64 + kt*32 + quad*8);
#pragma unroll
      for (int jl = 0; jl < 2; ++jl)
#pragma unroll
        for (int q_t = 0; q_t < 4; ++q_t)
          sacc[jl][q_t] = __builtin_amdgcn_mfma_f32_16x16x32_bf16(ak[jl], bq[q_t][kt], sacc[jl][q_t], 0, 0, 0);
    }
#pragma unroll
    for (int jl = 0; jl < 2; ++jl) {
      const int jrow = wj*64 + (jp*2+jl)*16 + quad*4;
      const uchar4 mk = *(const uchar4*)&mlds[jrow];
#pragma unroll
      for (int q_t = 0; q_t < 4; ++q_t) {
        const float e0 = mk.x ? 0.f : __expf(sacc[jl][q_t][0]);
        const float e1 = mk.y ? 0.f : __expf(sacc[jl][q_t][1]);
        const float e2 = mk.z ? 0.f : __expf(sacc[jl][q_t][2]);
        const float e3 = mk.w ? 0.f : __expf(sacc[jl][q_t][3]);
        lsum[q_t] += (e0 + e1) + (e2 + e3);
        const int qcol = wq*64 + q_t*16 + lm;
        *(uint2*)&Es[0][qcol*132 + jrow] = make_uint2(cvtpk(e0, e1), cvtpk(e2, e3));
      }
    }
  }

  // ---- main loop: one barrier per tile ----
  for (int jt = 0; jt < 16; ++jt) {
    const int cur = jt & 1;
    const int j0 = jt * 128;
    __syncthreads();   // Es[cur] visible; Es[cur^1] readers (PV t-1) done

    // K loads for tile jt+1 (issued early; PV hides their latency)
    short8 akn[2][4];
    if (jt < 15) {
      const int j0n = j0 + 128;
#pragma unroll
      for (int kt = 0; kt < 2; ++kt)
#pragma unroll
        for (int j_t = 0; j_t < 4; ++j_t)
          akn[kt][j_t] = *(const short8*)(kb + ((size_t)(j0n + wj*64 + j_t*16 + lm)*2 + n)*1024 + h*64 + kt*32 + quad*8);
    }

    // ---- PV(jt): A = Es[cur] rows q, B = V^T from global ----
#pragma unroll
    for (int kk = 0; kk < 4; ++kk) {
      S8U ae0, ae1;
      const int r0 = wid*32 + lm, r1 = r0 + 16;
      ae0.u[0] = *(const uint2*)&Es[cur][r0*132 + kk*32 + quad*8];
      ae0.u[1] = *(const uint2*)&Es[cur][r0*132 + kk*32 + quad*8 + 4];
      ae1.u[0] = *(const uint2*)&Es[cur][r1*132 + kk*32 + quad*8];
      ae1.u[1] = *(const uint2*)&Es[cur][r1*132 + kk*32 + quad*8 + 4];
      const unsigned short* vbase = vt + (size_t)((n*16 + h)*64)*2048 + j0 + kk*32 + quad*8;
#pragma unroll
      for (int dt = 0; dt < 4; ++dt) {
        const short8 bv = *(const short8*)(vbase + (size_t)(dt*16 + lm)*2048);
        oacc[0][dt] = __builtin_amdgcn_mfma_f32_16x16x32_bf16(ae0.v, bv, oacc[0][dt], 0, 0, 0);
        oacc[1][dt] = __builtin_amdgcn_mfma_f32_16x16x32_bf16(ae1.v, bv, oacc[1][dt], 0, 0, 0);
      }
    }

    // ---- QK^T(jt+1) + exp -> Es[cur^1], two j_t-pair passes ----
    if (jt < 15) {
#pragma unroll
      for (int jp = 0; jp < 2; ++jp) {
        f32x4 sacc[2][4];
#pragma unroll
        for (int a = 0; a < 2; ++a)
#pragma unroll
          for (int b = 0; b < 4; ++b) sacc[a][b] = 0.f;
#pragma unroll
        for (int kt = 0; kt < 2; ++kt)
#pragma unroll
          for (int jl = 0; jl < 2; ++jl)
#pragma unroll
            for (int q_t = 0; q_t < 4; ++q_t)
              sacc[jl][q_t] = __builtin_amdgcn_mfma_f32_16x16x32_bf16(akn[kt][jp*2+jl], bq[q_t][kt], sacc[jl][q_t], 0, 0, 0);
#pragma unroll
        for (int jl = 0; jl < 2; ++jl) {
          const int jrow = wj*64 + (jp*2+jl)*16 + quad*4;
          const uchar4 mk = *(const uchar4*)&mlds[j0 + 128 + jrow];
#pragma unroll
          for (int q_t = 0; q_t < 4; ++q_t) {
            const float e0 = mk.x ? 0.f : __expf(sacc[jl][q_t][0]);
            const float e1 = mk.y ? 0.f : __expf(sacc[jl][q_t][1]);
            const float e2 = mk.z ? 0.f : __expf(sacc[jl][q_t][2]);
            const float e3 = mk.w ? 0.f : __expf(sacc[jl][q_t][3]);
            lsum[q_t] += (e0 + e1) + (e2 + e3);
            const int qcol = wq*64 + q_t*16 + lm;
            *(uint2*)&Es[cur^1][qcol*132 + jrow] = make_uint2(cvtpk(e0, e1), cvtpk(e2, e3));
          }
        }
      }
    }
  }

  // ---- l reduction: 4 quads via shuffle, 2 wj halves via LDS ----
#pragma unroll
  for (int q_t = 0; q_t < 4; ++q_t) {
    float v = lsum[q_t];
    v += __shfl_xor(v, 16, 64);
    v += __shfl_xor(v, 32, 64);
    if (quad == 0) lred[wj][wq*64 + q_t*16 + lm] = v;
  }
  __syncthreads();
  if (tid < 128) {
    const float l = lred[0][tid] + lred[1][tid];
    const float rinv = 1.0f / fmaxf(l, FTINY);
    lred[0][tid] = rinv;
    msl[(size_t)(h*2 + n)*2048 + q0 + tid] = rinv;
  }
  __syncthreads();
  // ---- scale + write ctx ----
#pragma unroll
  for (int i2 = 0; i2 < 2; ++i2) {
    const int rb = wid*32 + i2*16 + quad*4;
    const float4 rv4 = *(const float4*)&lred[0][rb];
    const float rva[4] = {rv4.x, rv4.y, rv4.z, rv4.w};
#pragma unroll
    for (int dt = 0; dt < 4; ++dt) {
#pragma unroll
      for (int r = 0; r < 4; ++r) {
        ctx[((size_t)(q0 + rb + r)*2 + n)*1024 + h*64 + dt*16 + lm] =
            f2bf(oacc[i2][dt][r] * rva[r]);
      }
    }
  }
}

// ---------------------------------------------------------------------------
// wmean2: block = (128 q, 128 j, n), 256 thr, grid (16,16,2).  R18 exact.
// Loop h.  Zero LDS, zero barriers.  Q pre-scaled -> e = exp(S).
// ---------------------------------------------------------------------------
__global__ __launch_bounds__(256) void wmean2(
    const unsigned short* __restrict__ qb, const unsigned short* __restrict__ kb,
    const int* __restrict__ mask, const float* __restrict__ msl,
    float* __restrict__ wout)
{
  const int tid = threadIdx.x, lane = tid & 63, wid = tid >> 6;
  const int quad = lane >> 4, lm = lane & 15;
  const int q0 = blockIdx.x * 128, j0 = blockIdx.y * 128, n = blockIdx.z;
  const int wq = wid >> 1, wj = wid & 1;

  unsigned fm = 0;
#pragma unroll
  for (int j_t = 0; j_t < 4; ++j_t)
    fm |= (mask[n*2048 + j0 + wj*64 + j_t*16 + lm] != 0 ? 1u : 0u) << j_t;

  f32x4 wacc[4][4];
#pragma unroll
  for (int i = 0; i < 4; ++i)
#pragma unroll
    for (int j = 0; j < 4; ++j) wacc[i][j] = 0.f;

  for (int h = 0; h < 16; ++h) {
    short8 aq[4][2];
#pragma unroll
    for (int i = 0; i < 4; ++i) {
      const unsigned short* qg = qb + ((size_t)(q0 + wq*64 + i*16 + lm)*2 + n)*1024 + h*64 + quad*8;
      aq[i][0] = *(const short8*)qg;
      aq[i][1] = *(const short8*)(qg + 32);
    }
    float4 rv[4];
#pragma unroll
    for (int i = 0; i < 4; ++i)
      rv[i] = *(const float4*)&msl[(size_t)(h*2 + n)*2048 + q0 + wq*64 + i*16 + quad*4];
#pragma unroll
    for (int jh2 = 0; jh2 < 2; ++jh2) {
      short8 bk[2][2];
#pragma unroll
      for (int jtl = 0; jtl < 2; ++jtl) {
        const unsigned short* kg = kb + ((size_t)(j0 + wj*64 + (jh2*2 + jtl)*16 + lm)*2 + n)*1024 + h*64 + quad*8;
        bk[jtl][0] = *(const short8*)kg;
        bk[jtl][1] = *(const short8*)(kg + 32);
      }
      f32x4 sacc[4][2];
#pragma unroll
      for (int i = 0; i < 4; ++i)
#pragma unroll
        for (int jtl = 0; jtl < 2; ++jtl) sacc[i][jtl] = 0.f;
#pragma unroll
      for (int kt = 0; kt < 2; ++kt)
#pragma unroll
        for (int i = 0; i < 4; ++i)
#pragma unroll
          for (int jtl = 0; jtl < 2; ++jtl)
            sacc[i][jtl] = __builtin_amdgcn_mfma_f32_16x16x32_bf16(aq[i][kt], bk[jtl][kt], sacc[i][jtl], 0, 0, 0);
#pragma unroll
      for (int i = 0; i < 4; ++i) {
        const float rva[4] = {rv[i].x, rv[i].y, rv[i].z, rv[i].w};
#pragma unroll
        for (int jtl = 0; jtl < 2; ++jtl) {
          const int j_t = jh2*2 + jtl;
          const bool mskd = (fm >> j_t) & 1u;
#pragma unroll
          for (int r = 0; r < 4; ++r) {
            const float e = mskd ? 0.f : __expf(sacc[i][jtl][r]) * rva[r];
            wacc[i][j_t][r] += e;
          }
        }
      }
    }
  }
  // ---- store head-mean ----
#pragma unroll
  for (int i = 0; i < 4; ++i)
#pragma unroll
    for (int j_t = 0; j_t < 4; ++j_t)
#pragma unroll
      for (int r = 0; r < 4; ++r) {
        const int row = q0 + wq*64 + i*16 + quad*4 + r;
        const int col = j0 + wj*64 + j_t*16 + lm;
        wout[((size_t)row*2 + n)*2048 + col] = wacc[i][j_t][r] * 0.0625f;
      }
}

// ---------------------------------------------------------------------------
// ctx_copy: move ctx (bf16, 8.4 MB) from d_out region into kbuf.
// ---------------------------------------------------------------------------
__global__ __launch_bounds__(256) void ctx_copy(const uint4* __restrict__ src,
                                                uint4* __restrict__ dst)
{
  const size_t i = (size_t)blockIdx.x * 256 + threadIdx.x;
  dst[i] = src[i];
}

// ---------------------------------------------------------------------------
extern "C" void kernel_launch(void* const* d_in, const int* in_sizes, int n_in,
                              void* d_out, int out_size, void* d_ws, size_t ws_size,
                              hipStream_t stream) {
  const float* x    = (const float*)d_in[0];
  const int*   mask = (const int*)d_in[1];
  const float* Wq = (const float*)d_in[2];  const float* bq = (const float*)d_in[3];
  const float* Aq = (const float*)d_in[4];  const float* Bq = (const float*)d_in[5];
  const float* Wk = (const float*)d_in[6];  const float* bk = (const float*)d_in[7];
  const float* Ak = (const float*)d_in[8];  const float* Bk = (const float*)d_in[9];
  const float* Wv = (const float*)d_in[10]; const float* bv = (const float*)d_in[11];
  const float* Av = (const float*)d_in[12]; const float* Bv = (const float*)d_in[13];
  const float* Wo = (const float*)d_in[14]; const float* bo = (const float*)d_in[15];
  const float* Ao = (const float*)d_in[16]; const float* Bo = (const float*)d_in[17];

  float* outF = (float*)d_out;          // fp32: [4194304 attn | 8388608 weights]
  float* woutF = outF + 4194304;

  // d_ws: 24 MiB of bf16 internals
  unsigned short* kbuf = (unsigned short*)d_ws;   // [0, 8 MiB)
  unsigned short* vtb  = kbuf + 4194304;          // [8, 16 MiB)
  unsigned short* qbuf = vtb  + 4194304;          // [16, 24 MiB)

  // xaq/xak/xav at head of fp32 weights region (dead before wout overwrites)
  float* xaq = woutF;
  float* xak = xaq + 32768;
  float* xav = xak + 32768;

  // bf16 operand packs parked in the attn-output region (floats [0, 4194304)):
  //   Xbf  floats [0, 2097152)        -- dead after QKV gemm
  //   Wqbf floats [2097152, 2621440)  -- dead after QKV gemm
  //   Wkbf floats [2621440, 3145728)
  //   Wvbf floats [3145728, 3670016)
  // attn_pv then writes ctx16 at [0, 2097152) and msl at [2359296, 2424832).
  unsigned short* Xbf  = (unsigned short*)outF;
  unsigned short* Wqbf = (unsigned short*)(outF + 2097152);
  unsigned short* Wkbf = (unsigned short*)(outF + 2621440);
  unsigned short* Wvbf = (unsigned short*)(outF + 3145728);
  unsigned short* ctx16 = (unsigned short*)outF;
  float* msl = outF + 2359296;

  // xao overlays vtb[0,128KB); Wo-bf16 at vtb bytes [1MB,3MB) (V dead then)
  float* xao = (float*)vtb;
  unsigned short* Wobf = vtb + 524288;

  pack_bf16<<<dim3(2048), dim3(256), 0, stream>>>(x, Xbf);
  pack3_bf16<<<dim3(512, 3), dim3(256), 0, stream>>>(Wq, Wk, Wv, Wqbf, Wkbf, Wvbf);

  xa_kernel<<<dim3(4096), dim3(256), 0, stream>>>(Xbf, Aq, xaq);
  xa_kernel<<<dim3(4096), dim3(256), 0, stream>>>(Xbf, Ak, xak);
  xa_kernel<<<dim3(4096), dim3(256), 0, stream>>>(Xbf, Av, xav);

  // Q output pre-scaled by 0.125 (exact bf16 exponent shift)
  gemm_bf16<<<dim3(32, 8, 3), dim3(256), 0, stream>>>(
      Xbf, Wqbf, Wkbf, Wvbf, bq, bk, bv, xaq, xak, xav, Bq, Bk, Bv,
      qbuf, kbuf, vtb, 0, 0.125f);

  attn_pv<<<dim3(16, 2, 16), dim3(256), 0, stream>>>(qbuf, kbuf, vtb, mask, ctx16, msl);

  pack_bf16<<<dim3(512), dim3(256), 0, stream>>>(Wo, Wobf);   // vtb dead now

  wmean2<<<dim3(16, 16, 2), dim3(256), 0, stream>>>(qbuf, kbuf, mask, msl, woutF);

  // kbuf dead after wmean2 -> move ctx there
  ctx_copy<<<dim3(2048), dim3(256), 0, stream>>>((const uint4*)ctx16, (uint4*)kbuf);

  xa_kernel<<<dim3(4096), dim3(256), 0, stream>>>(kbuf, Ao, xao);

  gemm_bf16<<<dim3(32, 8, 1), dim3(256), 0, stream>>>(
      kbuf, Wobf, Wobf, Wobf, bo, bo, bo, xao, xao, xao, Bo, Bo, Bo,
      outF, outF, outF, 1, 1.0f);
}

// Round 12
// 462.043 us; speedup vs baseline: 1.1548x; 1.0263x over previous
//
#include <hip/hip_runtime.h>
#include <stdint.h>

// ============================================================================
// LoRA Multihead Attention, MI355X / gfx950.  Round 21.
// R20 post-mortem: dbuf/1-barrier pipeline EXACTLY neutral (126.7 vs 126.6us)
// -- compiler already schedules; barriers weren't the cost.  Reliable wins
// R15-R20 were all VALU cuts (cvtpk, scale-fold).  VALU 24.5% vs Mfma 10.6%:
// softmax block (cndmask + mul log2e + exp + fma) is the per-wave path.
// R21, pure exact-math VALU elimination:
//  (1) scale0 = 0.125*log2e folded into Q -> e = v_exp_f32(S) direct
//      (saves a v_mul per element in attn_pv AND wmean2);
//  (2) mask as MFMA C-init: per-j bias (0/-3e38) floats passed as QK
//      accumulator init (rows=j swapped) -> exp2(-3e38)=0 exactly; all
//      cndmask + mask reads in the inner loop vanish;
//  (3) wmean2: msl = -log2(max(l,tiny)) - 4; C-init = msl[q] (rows=q) ->
//      inner loop is wacc += exp2(sacc); rinv-fma and in-loop mask gone
//      (mask applied at store, 16 cndmask amortized over 16 heads).
// attn_pv reverts to R18 single-buffer loop.  xa x3 -> one z-grid dispatch.
// Predict: attn_pv 126.6 -> ~105-112 (VALU ~17%), wmean2 ~95 -> ~70,
// total 474 -> ~425-440.  absmax may rise to ~0.0035 (extra Q rounding).
// ============================================================================

typedef __attribute__((ext_vector_type(8))) short short8;   // 8 x bf16 (4 VGPR)
typedef __attribute__((ext_vector_type(4))) float f32x4;    // MFMA C/D

#define LORA_SCALING 4.0f   // ALPHA/R = 32/8
#define FTINY 1.1754943508222875e-38f
#define QSCALE 0.18033688011112042f   // 0.125 * log2(e)

static __device__ __forceinline__ unsigned short f2bf(float f){ // RN-even
  unsigned u = __float_as_uint(f);
  u += 0x7fffu + ((u >> 16) & 1u);
  return (unsigned short)(u >> 16);
}
static __device__ __forceinline__ float bflo(unsigned u){ return __uint_as_float(u << 16); }
static __device__ __forceinline__ float bfhi(unsigned u){ return __uint_as_float(u & 0xffff0000u); }
static __device__ __forceinline__ unsigned pk2(float lo, float hi){
  return (unsigned)f2bf(lo) | ((unsigned)f2bf(hi) << 16);
}
static __device__ __forceinline__ unsigned cvtpk(float lo, float hi){ // RNE pack
  unsigned r;
  asm("v_cvt_pk_bf16_f32 %0, %1, %2" : "=v"(r) : "v"(lo), "v"(hi));
  return r;
}
static __device__ __forceinline__ float vexp2(float x){ // 2^x
  float r;
  asm("v_exp_f32 %0, %1" : "=v"(r) : "v"(x));
  return r;
}
static __device__ __forceinline__ float vlog2(float x){ // log2(x)
  float r;
  asm("v_log_f32 %0, %1" : "=v"(r) : "v"(x));
  return r;
}
static __device__ __forceinline__ f32x4 f4v(float4 t){
  f32x4 v; v[0]=t.x; v[1]=t.y; v[2]=t.z; v[3]=t.w; return v;
}
static __device__ __forceinline__ void gload16(const void* g, void* l){
  __builtin_amdgcn_global_load_lds(
      (const __attribute__((address_space(1))) unsigned int*)g,
      (__attribute__((address_space(3))) unsigned int*)l, 16, 0, 0);
}

union S8U { short8 v; uint2 u[2]; };

// ---------------------------------------------------------------------------
// pack_bf16: fp32 -> bf16 (RN-even), 8 elems/thread.  pack3: z picks src.
// ---------------------------------------------------------------------------
__global__ __launch_bounds__(256) void pack_bf16(const float* __restrict__ src,
                                                 unsigned short* __restrict__ dst)
{
  const size_t i = (size_t)blockIdx.x * 256 + threadIdx.x;   // 8-elem group
  const float4 f0 = ((const float4*)src)[i*2];
  const float4 f1 = ((const float4*)src)[i*2 + 1];
  ((uint4*)dst)[i] = make_uint4(pk2(f0.x,f0.y), pk2(f0.z,f0.w),
                                pk2(f1.x,f1.y), pk2(f1.z,f1.w));
}
__global__ __launch_bounds__(256) void pack3_bf16(
    const float* __restrict__ s0, const float* __restrict__ s1, const float* __restrict__ s2,
    unsigned short* __restrict__ d0, unsigned short* __restrict__ d1,
    unsigned short* __restrict__ d2)
{
  const int z = blockIdx.y;
  const float* src = (z==0)?s0:((z==1)?s1:s2);
  unsigned short* dst = (z==0)?d0:((z==1)?d1:d2);
  const size_t i = (size_t)blockIdx.x * 256 + threadIdx.x;
  const float4 f0 = ((const float4*)src)[i*2];
  const float4 f1 = ((const float4*)src)[i*2 + 1];
  ((uint4*)dst)[i] = make_uint4(pk2(f0.x,f0.y), pk2(f0.z,f0.w),
                                pk2(f1.x,f1.y), pk2(f1.z,f1.w));
}

// ---------------------------------------------------------------------------
// xa3[t][r] = sum_i x[t][i] * A[r][i]  for 3 A matrices (z).  X is bf16.
// ---------------------------------------------------------------------------
__global__ __launch_bounds__(256) void xa3_kernel(
    const unsigned short* __restrict__ X,
    const float* __restrict__ A0, const float* __restrict__ A1,
    const float* __restrict__ A2,
    float* __restrict__ x0p, float* __restrict__ x1p, float* __restrict__ x2p)
{
  __shared__ float red[4][8];
  const int z = blockIdx.y;
  const float* A = (z==0)?A0:((z==1)?A1:A2);
  float* xa = (z==0)?x0p:((z==1)?x1p:x2p);
  const int t = blockIdx.x, tid = threadIdx.x;
  const int lane = tid & 63, wid = tid >> 6;

  const uint2 xr = *(const uint2*)(X + (size_t)t*1024 + tid*4);
  const float x0 = bflo(xr.x), x1 = bfhi(xr.x), x2 = bflo(xr.y), x3 = bfhi(xr.y);

  float acc[8];
#pragma unroll
  for (int r = 0; r < 8; ++r) {
    const float4 ar = *(const float4*)(A + (size_t)r*1024 + tid*4);
    acc[r] = x0*ar.x + x1*ar.y + x2*ar.z + x3*ar.w;
  }
#pragma unroll
  for (int r = 0; r < 8; ++r) {
    float v = acc[r];
#pragma unroll
    for (int off = 32; off > 0; off >>= 1) v += __shfl_xor(v, off, 64);
    if (lane == 0) red[wid][r] = v;
  }
  __syncthreads();
  if (tid < 8) xa[(size_t)t*8 + tid] = red[0][tid] + red[1][tid] + red[2][tid] + red[3][tid];
}

// single-input variant (for ctx)
__global__ __launch_bounds__(256) void xa_kernel(const unsigned short* __restrict__ X,
                                                 const float* __restrict__ A,
                                                 float* __restrict__ xa)
{
  __shared__ float red[4][8];
  const int t = blockIdx.x, tid = threadIdx.x;
  const int lane = tid & 63, wid = tid >> 6;

  const uint2 xr = *(const uint2*)(X + (size_t)t*1024 + tid*4);
  const float x0 = bflo(xr.x), x1 = bfhi(xr.x), x2 = bflo(xr.y), x3 = bfhi(xr.y);

  float acc[8];
#pragma unroll
  for (int r = 0; r < 8; ++r) {
    const float4 ar = *(const float4*)(A + (size_t)r*1024 + tid*4);
    acc[r] = x0*ar.x + x1*ar.y + x2*ar.z + x3*ar.w;
  }
#pragma unroll
  for (int r = 0; r < 8; ++r) {
    float v = acc[r];
#pragma unroll
    for (int off = 32; off > 0; off >>= 1) v += __shfl_xor(v, off, 64);
    if (lane == 0) red[wid][r] = v;
  }
  __syncthreads();
  if (tid < 8) xa[(size_t)t*8 + tid] = red[0][tid] + red[1][tid] + red[2][tid] + red[3][tid];
}

// ---------------------------------------------------------------------------
// C = X(4096x1024 bf16) * W(1024x1024 bf16)^T + bias + 4 * xa * Blora^T.
// MFMA 16x16x32, 128x128 tile, BK=32.  Staging via global_load_lds(16).
// z==0 output scaled by scale0 (QSCALE for Q: 0.125*log2e folded).
// ---------------------------------------------------------------------------
__global__ __launch_bounds__(256) void gemm_bf16(
    const unsigned short* __restrict__ Abf,
    const unsigned short* __restrict__ W0bf, const unsigned short* __restrict__ W1bf,
    const unsigned short* __restrict__ W2bf,
    const float* __restrict__ B0, const float* __restrict__ B1, const float* __restrict__ B2,
    const float* __restrict__ xa0, const float* __restrict__ xa1, const float* __restrict__ xa2,
    const float* __restrict__ L0, const float* __restrict__ L1, const float* __restrict__ L2,
    void* __restrict__ C0, void* __restrict__ C1, void* __restrict__ C2,
    int fp32out, float scale0)
{
  const int z = blockIdx.z;
  const unsigned short* W = (z==0)?W0bf:((z==1)?W1bf:W2bf);
  const float* Bb = (z==0)?B0:((z==1)?B1:B2);
  const float* xa = (z==0)?xa0:((z==1)?xa1:xa2);
  const float* Lb = (z==0)?L0:((z==1)?L1:L2);
  void*        C  = (z==0)?C0:((z==1)?C1:C2);
  const bool vtw = (z == 2);
  const float sc = (z == 0) ? scale0 : 1.0f;

  __shared__ alignas(16) unsigned short As[128*32];
  __shared__ alignas(16) unsigned short Bs[128*32];

  const int tid = threadIdx.x;
  const int lane = tid & 63, wid = tid >> 6;
  const int quad = lane >> 4, lm = lane & 15;
  const int t0 = blockIdx.x * 128, n0 = blockIdx.y * 128;
  const int wm = (wid & 1) * 64, wn = (wid >> 1) * 64;

  // 16B chunk ids for staging (row = c>>2, col elems = (c&3)*8)
  const int c0 = tid, c1 = tid + 256;
  const int r0c = c0 >> 2, e0c = (c0 & 3) * 8;
  const int r1c = c1 >> 2, e1c = (c1 & 3) * 8;

  f32x4 acc[4][4];
#pragma unroll
  for (int i = 0; i < 4; ++i)
#pragma unroll
    for (int j = 0; j < 4; ++j) acc[i][j] = 0.f;

  for (int kt = 0; kt < 32; ++kt) {
    const int k0 = kt * 32;
    __syncthreads();   // previous iteration's fragment reads complete
    gload16(Abf + (size_t)(t0 + r0c)*1024 + k0 + e0c, &As[c0*8]);
    gload16(Abf + (size_t)(t0 + r1c)*1024 + k0 + e1c, &As[c1*8]);
    gload16(W   + (size_t)(n0 + r0c)*1024 + k0 + e0c, &Bs[c0*8]);
    gload16(W   + (size_t)(n0 + r1c)*1024 + k0 + e1c, &Bs[c1*8]);
    __syncthreads();   // vmcnt(0) drained before barrier -> LDS visible
    short8 a[4], b[4];
#pragma unroll
    for (int i = 0; i < 4; ++i) a[i] = *(const short8*)&As[(wm + i*16 + lm)*32 + quad*8];
#pragma unroll
    for (int j = 0; j < 4; ++j) b[j] = *(const short8*)&Bs[(wn + j*16 + lm)*32 + quad*8];
#pragma unroll
    for (int i = 0; i < 4; ++i)
#pragma unroll
      for (int j = 0; j < 4; ++j)
        acc[i][j] = __builtin_amdgcn_mfma_f32_16x16x32_bf16(a[i], b[j], acc[i][j], 0, 0, 0);
  }

  // epilogue: (bias + 4.0 * (xa . Blora) + acc) * sc
#pragma unroll
  for (int j = 0; j < 4; ++j) {
    const int col = n0 + wn + j*16 + lm;
    const float bias = Bb[col];
    const float4 u0 = ((const float4*)(Lb + (size_t)col*8))[0];
    const float4 u1 = ((const float4*)(Lb + (size_t)col*8))[1];
#pragma unroll
    for (int i = 0; i < 4; ++i) {
#pragma unroll
      for (int r = 0; r < 4; ++r) {
        const int row = t0 + wm + i*16 + quad*4 + r;
        const float* xr = xa + (size_t)row*8;
        const float lora = xr[0]*u0.x + xr[1]*u0.y + xr[2]*u0.z + xr[3]*u0.w
                         + xr[4]*u1.x + xr[5]*u1.y + xr[6]*u1.z + xr[7]*u1.w;
        const float val = (acc[i][j][r] + bias + LORA_SCALING*lora) * sc;
        if (fp32out) {
          ((float*)C)[(size_t)row*1024 + col] = val;
        } else if (vtw) {
          // t = l*2 + n  ->  Vt[(n*1024 + e)*2048 + l]
          ((unsigned short*)C)[((size_t)(row & 1) * 1024 + col) * 2048 + (row >> 1)] = f2bf(val);
        } else {
          ((unsigned short*)C)[(size_t)row*1024 + col] = f2bf(val);
        }
      }
    }
  }
}

// ---------------------------------------------------------------------------
// attn_pv: block = (128 q, n, h), 256 thr, grid (16,2,16).  R18 single-buffer
// loop.  Q pre-scaled by 0.125*log2e -> e = exp2(S).  Mask folded into the
// QK MFMA C-init (bias 0/-3e38 per j row; exp2(-3e38)=0 exactly) -- no
// cndmask/mask reads in the inner loop.  End: l reduce, ctx = oacc*rinv,
// msl = -log2(max(l,tiny)) - 4  (consumed by wmean2 as exponent offset).
// ---------------------------------------------------------------------------
__global__ __launch_bounds__(256) void attn_pv(
    const unsigned short* __restrict__ qb, const unsigned short* __restrict__ kb,
    const unsigned short* __restrict__ vt, const int* __restrict__ mask,
    unsigned short* __restrict__ ctx, float* __restrict__ msl)
{
  __shared__ alignas(16) unsigned short Es[128*132];   // e-tile [q][j], pad 4
  __shared__ float mbias[2048];                        // per-j bias 0/-3e38
  __shared__ float lred[2][128];

  const int tid = threadIdx.x, lane = tid & 63, wid = tid >> 6;  // wid 0..3
  const int quad = lane >> 4, lm = lane & 15;
  const int q0 = blockIdx.x * 128, n = blockIdx.y, h = blockIdx.z;
  const int wq = wid >> 1, wj = wid & 1;

  // stage bias floats for all 2048 j
  {
    const int4 m0 = *(const int4*)(mask + n*2048 + tid*8);
    const int4 m1 = *(const int4*)(mask + n*2048 + tid*8 + 4);
    mbias[tid*8+0] = m0.x ? -3.0e38f : 0.f;
    mbias[tid*8+1] = m0.y ? -3.0e38f : 0.f;
    mbias[tid*8+2] = m0.z ? -3.0e38f : 0.f;
    mbias[tid*8+3] = m0.w ? -3.0e38f : 0.f;
    mbias[tid*8+4] = m1.x ? -3.0e38f : 0.f;
    mbias[tid*8+5] = m1.y ? -3.0e38f : 0.f;
    mbias[tid*8+6] = m1.z ? -3.0e38f : 0.f;
    mbias[tid*8+7] = m1.w ? -3.0e38f : 0.f;
  }

  // Q as B-operand fragments, in registers for the whole block
  short8 bq[4][2];
#pragma unroll
  for (int q_t = 0; q_t < 4; ++q_t) {
    const unsigned short* qg = qb + ((size_t)(q0 + wq*64 + q_t*16 + lm)*2 + n)*1024 + h*64 + quad*8;
    bq[q_t][0] = *(const short8*)qg;
    bq[q_t][1] = *(const short8*)(qg + 32);
  }

  float lsum[4] = {0.f, 0.f, 0.f, 0.f};
  f32x4 oacc[2][4];
#pragma unroll
  for (int i2 = 0; i2 < 2; ++i2)
#pragma unroll
    for (int dt = 0; dt < 4; ++dt) oacc[i2][dt] = 0.f;

  for (int jt = 0; jt < 16; ++jt) {
    const int j0 = jt * 128;
    __syncthreads();   // Es free (prev PV reads done); mbias visible (jt==0)

    // ---- QK^T swapped: sacc[j_t][q_t], rows j, cols q; C-init = bias ----
    f32x4 sacc[4][4];
#pragma unroll
    for (int kt = 0; kt < 2; ++kt) {
      short8 ak[4];
#pragma unroll
      for (int j_t = 0; j_t < 4; ++j_t)
        ak[j_t] = *(const short8*)(kb + ((size_t)(j0 + wj*64 + j_t*16 + lm)*2 + n)*1024 + h*64 + kt*32 + quad*8);
      if (kt == 0) {
#pragma unroll
        for (int j_t = 0; j_t < 4; ++j_t) {
          const f32x4 bini = f4v(*(const float4*)&mbias[j0 + wj*64 + j_t*16 + quad*4]);
#pragma unroll
          for (int q_t = 0; q_t < 4; ++q_t)
            sacc[j_t][q_t] = __builtin_amdgcn_mfma_f32_16x16x32_bf16(ak[j_t], bq[q_t][0], bini, 0, 0, 0);
        }
      } else {
#pragma unroll
        for (int j_t = 0; j_t < 4; ++j_t)
#pragma unroll
          for (int q_t = 0; q_t < 4; ++q_t)
            sacc[j_t][q_t] = __builtin_amdgcn_mfma_f32_16x16x32_bf16(ak[j_t], bq[q_t][1], sacc[j_t][q_t], 0, 0, 0);
      }
    }
    // ---- exp2 + lsum + Es writes (cvt_pk); no mask ops ----
#pragma unroll
    for (int j_t = 0; j_t < 4; ++j_t) {
      const int jrow = wj*64 + j_t*16 + quad*4;            // local j of rows r=0..3
#pragma unroll
      for (int q_t = 0; q_t < 4; ++q_t) {
        const float e0 = vexp2(sacc[j_t][q_t][0]);
        const float e1 = vexp2(sacc[j_t][q_t][1]);
        const float e2 = vexp2(sacc[j_t][q_t][2]);
        const float e3 = vexp2(sacc[j_t][q_t][3]);
        lsum[q_t] += (e0 + e1) + (e2 + e3);
        const int qcol = wq*64 + q_t*16 + lm;
        *(uint2*)&Es[qcol*132 + jrow] = make_uint2(cvtpk(e0, e1), cvtpk(e2, e3));
      }
    }
    __syncthreads();   // Es visible
    // ---- PV: A = Es rows q, B = V^T from global ----
#pragma unroll
    for (int kk = 0; kk < 4; ++kk) {
      S8U ae0, ae1;
      const int r0 = wid*32 + lm, r1 = r0 + 16;
      ae0.u[0] = *(const uint2*)&Es[r0*132 + kk*32 + quad*8];
      ae0.u[1] = *(const uint2*)&Es[r0*132 + kk*32 + quad*8 + 4];
      ae1.u[0] = *(const uint2*)&Es[r1*132 + kk*32 + quad*8];
      ae1.u[1] = *(const uint2*)&Es[r1*132 + kk*32 + quad*8 + 4];
      const unsigned short* vbase = vt + (size_t)((n*16 + h)*64)*2048 + j0 + kk*32 + quad*8;
#pragma unroll
      for (int dt = 0; dt < 4; ++dt) {
        const short8 bv = *(const short8*)(vbase + (size_t)(dt*16 + lm)*2048);
        oacc[0][dt] = __builtin_amdgcn_mfma_f32_16x16x32_bf16(ae0.v, bv, oacc[0][dt], 0, 0, 0);
        oacc[1][dt] = __builtin_amdgcn_mfma_f32_16x16x32_bf16(ae1.v, bv, oacc[1][dt], 0, 0, 0);
      }
    }
  }

  // ---- l reduction: 4 quads via shuffle, 2 wj halves via LDS ----
#pragma unroll
  for (int q_t = 0; q_t < 4; ++q_t) {
    float v = lsum[q_t];
    v += __shfl_xor(v, 16, 64);
    v += __shfl_xor(v, 32, 64);
    if (quad == 0) lred[wj][wq*64 + q_t*16 + lm] = v;
  }
  __syncthreads();
  if (tid < 128) {
    const float l = fmaxf(lred[0][tid] + lred[1][tid], FTINY);
    lred[0][tid] = 1.0f / l;
    msl[(size_t)(h*2 + n)*2048 + q0 + tid] = -vlog2(l) - 4.0f;  // for wmean2
  }
  __syncthreads();
  // ---- scale + write ctx ----
#pragma unroll
  for (int i2 = 0; i2 < 2; ++i2) {
    const int rb = wid*32 + i2*16 + quad*4;
    const float4 rv4 = *(const float4*)&lred[0][rb];
    const float rva[4] = {rv4.x, rv4.y, rv4.z, rv4.w};
#pragma unroll
    for (int dt = 0; dt < 4; ++dt) {
#pragma unroll
      for (int r = 0; r < 4; ++r) {
        ctx[((size_t)(q0 + rb + r)*2 + n)*1024 + h*64 + dt*16 + lm] =
            f2bf(oacc[i2][dt][r] * rva[r]);
      }
    }
  }
}

// ---------------------------------------------------------------------------
// wmean2: block = (128 q, 128 j, n), 256 thr, grid (16,16,2).  Loop h.
// Zero LDS, zero barriers.  msl holds -log2(l)-4 -> C-init = msl[q] folds
// rinv AND the /16 into the exponent: inner loop is wacc += exp2(sacc).
// Mask applied at store time (per-j columns -> 0), amortized over 16 h.
// ---------------------------------------------------------------------------
__global__ __launch_bounds__(256) void wmean2(
    const unsigned short* __restrict__ qb, const unsigned short* __restrict__ kb,
    const int* __restrict__ mask, const float* __restrict__ msl,
    float* __restrict__ wout)
{
  const int tid = threadIdx.x, lane = tid & 63, wid = tid >> 6;
  const int quad = lane >> 4, lm = lane & 15;
  const int q0 = blockIdx.x * 128, j0 = blockIdx.y * 128, n = blockIdx.z;
  const int wq = wid >> 1, wj = wid & 1;

  unsigned fm = 0;
#pragma unroll
  for (int j_t = 0; j_t < 4; ++j_t)
    fm |= (mask[n*2048 + j0 + wj*64 + j_t*16 + lm] != 0 ? 1u : 0u) << j_t;

  f32x4 wacc[4][4];
#pragma unroll
  for (int i = 0; i < 4; ++i)
#pragma unroll
    for (int j = 0; j < 4; ++j) wacc[i][j] = 0.f;

  for (int h = 0; h < 16; ++h) {
    short8 aq[4][2];
#pragma unroll
    for (int i = 0; i < 4; ++i) {
      const unsigned short* qg = qb + ((size_t)(q0 + wq*64 + i*16 + lm)*2 + n)*1024 + h*64 + quad*8;
      aq[i][0] = *(const short8*)qg;
      aq[i][1] = *(const short8*)(qg + 32);
    }
    f32x4 lr[4];
#pragma unroll
    for (int i = 0; i < 4; ++i)
      lr[i] = f4v(*(const float4*)&msl[(size_t)(h*2 + n)*2048 + q0 + wq*64 + i*16 + quad*4]);
#pragma unroll
    for (int jh2 = 0; jh2 < 2; ++jh2) {
      short8 bk[2][2];
#pragma unroll
      for (int jtl = 0; jtl < 2; ++jtl) {
        const unsigned short* kg = kb + ((size_t)(j0 + wj*64 + (jh2*2 + jtl)*16 + lm)*2 + n)*1024 + h*64 + quad*8;
        bk[jtl][0] = *(const short8*)kg;
        bk[jtl][1] = *(const short8*)(kg + 32);
      }
      f32x4 sacc[4][2];
#pragma unroll
      for (int i = 0; i < 4; ++i)
#pragma unroll
        for (int jtl = 0; jtl < 2; ++jtl)
          sacc[i][jtl] = __builtin_amdgcn_mfma_f32_16x16x32_bf16(aq[i][0], bk[jtl][0], lr[i], 0, 0, 0);
#pragma unroll
      for (int i = 0; i < 4; ++i)
#pragma unroll
        for (int jtl = 0; jtl < 2; ++jtl)
          sacc[i][jtl] = __builtin_amdgcn_mfma_f32_16x16x32_bf16(aq[i][1], bk[jtl][1], sacc[i][jtl], 0, 0, 0);
#pragma unroll
      for (int i = 0; i < 4; ++i)
#pragma unroll
        for (int jtl = 0; jtl < 2; ++jtl) {
          const int j_t = jh2*2 + jtl;
#pragma unroll
          for (int r = 0; r < 4; ++r)
            wacc[i][j_t][r] += vexp2(sacc[i][jtl][r]);
        }
    }
  }
  // ---- store head-mean (mask -> 0; /16 and rinv already in exponent) ----
#pragma unroll
  for (int i = 0; i < 4; ++i)
#pragma unroll
    for (int j_t = 0; j_t < 4; ++j_t) {
      const bool mskd = (fm >> j_t) & 1u;
#pragma unroll
      for (int r = 0; r < 4; ++r) {
        const int row = q0 + wq*64 + i*16 + quad*4 + r;
        const int col = j0 + wj*64 + j_t*16 + lm;
        wout[((size_t)row*2 + n)*2048 + col] = mskd ? 0.f : wacc[i][j_t][r];
      }
    }
}

// ---------------------------------------------------------------------------
// ctx_copy: move ctx (bf16, 8.4 MB) from d_out region into kbuf.
// ---------------------------------------------------------------------------
__global__ __launch_bounds__(256) void ctx_copy(const uint4* __restrict__ src,
                                                uint4* __restrict__ dst)
{
  const size_t i = (size_t)blockIdx.x * 256 + threadIdx.x;
  dst[i] = src[i];
}

// ---------------------------------------------------------------------------
extern "C" void kernel_launch(void* const* d_in, const int* in_sizes, int n_in,
                              void* d_out, int out_size, void* d_ws, size_t ws_size,
                              hipStream_t stream) {
  const float* x    = (const float*)d_in[0];
  const int*   mask = (const int*)d_in[1];
  const float* Wq = (const float*)d_in[2];  const float* bq = (const float*)d_in[3];
  const float* Aq = (const float*)d_in[4];  const float* Bq = (const float*)d_in[5];
  const float* Wk = (const float*)d_in[6];  const float* bk = (const float*)d_in[7];
  const float* Ak = (const float*)d_in[8];  const float* Bk = (const float*)d_in[9];
  const float* Wv = (const float*)d_in[10]; const float* bv = (const float*)d_in[11];
  const float* Av = (const float*)d_in[12]; const float* Bv = (const float*)d_in[13];
  const float* Wo = (const float*)d_in[14]; const float* bo = (const float*)d_in[15];
  const float* Ao = (const float*)d_in[16]; const float* Bo = (const float*)d_in[17];

  float* outF = (float*)d_out;          // fp32: [4194304 attn | 8388608 weights]
  float* woutF = outF + 4194304;

  // d_ws: 24 MiB of bf16 internals
  unsigned short* kbuf = (unsigned short*)d_ws;   // [0, 8 MiB)
  unsigned short* vtb  = kbuf + 4194304;          // [8, 16 MiB)
  unsigned short* qbuf = vtb  + 4194304;          // [16, 24 MiB)

  // xaq/xak/xav at head of fp32 weights region (dead before wout overwrites)
  float* xaq = woutF;
  float* xak = xaq + 32768;
  float* xav = xak + 32768;

  // bf16 operand packs parked in the attn-output region (floats [0, 4194304)):
  //   Xbf  floats [0, 2097152)        -- dead after QKV gemm
  //   Wqbf floats [2097152, 2621440)  -- dead after QKV gemm
  //   Wkbf floats [2621440, 3145728)
  //   Wvbf floats [3145728, 3670016)
  // attn_pv then writes ctx16 at [0, 2097152) and msl at [2359296, 2424832).
  unsigned short* Xbf  = (unsigned short*)outF;
  unsigned short* Wqbf = (unsigned short*)(outF + 2097152);
  unsigned short* Wkbf = (unsigned short*)(outF + 2621440);
  unsigned short* Wvbf = (unsigned short*)(outF + 3145728);
  unsigned short* ctx16 = (unsigned short*)outF;
  float* msl = outF + 2359296;

  // xao overlays vtb[0,128KB); Wo-bf16 at vtb bytes [1MB,3MB) (V dead then)
  float* xao = (float*)vtb;
  unsigned short* Wobf = vtb + 524288;

  pack_bf16<<<dim3(2048), dim3(256), 0, stream>>>(x, Xbf);
  pack3_bf16<<<dim3(512, 3), dim3(256), 0, stream>>>(Wq, Wk, Wv, Wqbf, Wkbf, Wvbf);

  xa3_kernel<<<dim3(4096, 3), dim3(256), 0, stream>>>(Xbf, Aq, Ak, Av, xaq, xak, xav);

  // Q output pre-scaled by 0.125*log2e (exp2 path)
  gemm_bf16<<<dim3(32, 8, 3), dim3(256), 0, stream>>>(
      Xbf, Wqbf, Wkbf, Wvbf, bq, bk, bv, xaq, xak, xav, Bq, Bk, Bv,
      qbuf, kbuf, vtb, 0, QSCALE);

  attn_pv<<<dim3(16, 2, 16), dim3(256), 0, stream>>>(qbuf, kbuf, vtb, mask, ctx16, msl);

  pack_bf16<<<dim3(512), dim3(256), 0, stream>>>(Wo, Wobf);   // vtb dead now

  wmean2<<<dim3(16, 16, 2), dim3(256), 0, stream>>>(qbuf, kbuf, mask, msl, woutF);

  // kbuf dead after wmean2 -> move ctx there
  ctx_copy<<<dim3(2048), dim3(256), 0, stream>>>((const uint4*)ctx16, (uint4*)kbuf);

  xa_kernel<<<dim3(4096), dim3(256), 0, stream>>>(kbuf, Ao, xao);

  gemm_bf16<<<dim3(32, 8, 1), dim3(256), 0, stream>>>(
      kbuf, Wobf, Wobf, Wobf, bo, bo, bo, xao, xao, xao, Bo, Bo, Bo,
      outF, outF, outF, 1, 1.0f);
}